// Round 4
// baseline (308.783 us; speedup 1.0000x reference)
//
#include <hip/hip_runtime.h>

// Top2Gating, S=8192, E=64, capacity=256. Output f32 flat:
//   [ l_aux (1) | combine (S*E*CAP) | dispatch (S*E*CAP) ]  = 1+2*SEC words.
// No memset: a final dense-writer kernel emits every output word exactly once
// (zeros + fused nonzeros). Intermediates live at chunk/token block heads
// inside d_out and are consumed strictly before being overwritten
// (ordering via stream kernel boundaries + self-block read->sync->write).

namespace {
constexpr int  TOK  = 8192;
constexpr int  NEXP = 64;
constexpr int  CAPC = 256;
constexpr int  CHK  = 128;
constexpr int  NCHK = TOK / CHK;                    // 64
constexpr long long TBLK = (long long)NEXP * CAPC;  // 16384 words per (token,section) block
constexpr long long TERR = (long long)CHK * TBLK;   // words per chunk territory
constexpr long long SEC  = (long long)TOK * TBLK;   // words per dense section
constexpr float NEGMIN = -3.402823466e38f;          // finfo(f32).min
constexpr float EPSF   = 1.1920929e-7f;             // finfo(f32).eps
// chunk raw record @ comb head (word offsets): i12[128]@0 g1[128]@128 g2[128]@256
//   h1[64]@384 h2[64]@448 me[64]@512   (phase2 overwrites h1/h2 with b1/b2full)
// per-token record (phase3 -> head of each token-section block, 4 words):
//   w0: i1 | i2<<8 | k1<<16 | k2<<17   w1: loc1 | loc2<<16   w2: w1(f32)  w3: w2(f32)
}

__device__ __forceinline__ float wave_max64(float v) {
    for (int o = 32; o; o >>= 1) v = fmaxf(v, __shfl_xor(v, o));
    return v;
}
__device__ __forceinline__ float wave_sum64(float v) {
    for (int o = 32; o; o >>= 1) v += __shfl_xor(v, o);
    return v;
}
__device__ __forceinline__ float* raw_base(float* out, int c) { return out + 1 + (long long)c * TERR; }

// ---- Phase 1: per-row softmax + top1/top2 (first-max semantics), per-chunk hist/me.
__global__ __launch_bounds__(256) void tg_gate(const float* __restrict__ logits,
                                               const float* __restrict__ noise,
                                               float* __restrict__ out)
{
    __shared__ int   h1[NEXP], h2[NEXP];
    __shared__ float meSh[256];
    const int tid = threadIdx.x, lane = tid & 63, wv = tid >> 6;
    const int c = blockIdx.x;
    float* raw = raw_base(out, c);

    if (tid < NEXP) { h1[tid] = 0; h2[tid] = 0; }
    __syncthreads();

    float meAcc = 0.f;
    for (int i = 0; i < CHK / 4; ++i) {
        const int rloc = i * 4 + wv;
        const int row  = c * CHK + rloc;
        const float l = logits[row * NEXP + lane];
        const float n = noise [row * NEXP + lane];

        const float m    = wave_max64(l);
        const float ex   = __expf(l - m);
        const float sm   = wave_sum64(ex);
        const float gate = ex / sm;

        const unsigned long long b1 = __ballot(l == m);    // argmax(gates)==argmax(logits)
        const int   i1 = __ffsll(b1) - 1;                  // first max wins (jnp.argmax)
        const float G1 = __shfl(gate, i1);

        const float lw = (lane == i1) ? NEGMIN : (l + n);  // mask winner with finfo.min
        const float m2 = wave_max64(lw);
        const unsigned long long b2 = __ballot(lw == m2);
        const int   i2 = __ffsll(b2) - 1;
        const float G2 = __shfl(gate, i2);

        if (lane == 0) {
            ((int*)raw)[rloc] = i1 | (i2 << 8);
            raw[128 + rloc]   = G1;
            raw[256 + rloc]   = G2;
            atomicAdd(&h1[i1], 1);
            atomicAdd(&h2[i2], 1);
        }
        meAcc += gate;
    }

    meSh[tid] = meAcc;
    __syncthreads();
    if (tid < NEXP) {
        ((int*)raw)[384 + tid] = h1[tid];
        ((int*)raw)[448 + tid] = h2[tid];
        raw[512 + tid] = meSh[tid] + meSh[64 + tid] + meSh[128 + tid] + meSh[192 + tid];
    }
}

// ---- Phase 2: LDS-staged cross-chunk exclusive scan; bases written back in place
//      of h1/h2; l_aux -> out[0].
__global__ __launch_bounds__(256) void tg_prefix(float* __restrict__ out)
{
    __shared__ int   h1s[NCHK][NEXP];
    __shared__ int   h2s[NCHK][NEXP];
    __shared__ float mes[NCHK][NEXP];
    const int tid = threadIdx.x;

    for (int n = tid; n < NCHK * 192; n += 256) {          // stage words 384..575 of each chunk
        const int c = n / 192, w = n % 192;
        float* raw = raw_base(out, c);
        if      (w < 64)  h1s[c][w]       = ((int*)raw)[384 + w];
        else if (w < 128) h2s[c][w - 64]  = ((int*)raw)[384 + w];
        else              mes[c][w - 128] = raw[384 + w];
    }
    __syncthreads();

    if (tid < NEXP) {
        const int e = tid;
        int r1 = 0, r2 = 0;
        float ms = 0.f;
        for (int c = 0; c < NCHK; ++c) {                   // b1 = exclusive prefix of h1
            ((int*)raw_base(out, c))[384 + e] = r1;
            r1 += h1s[c][e];
            r2 += h2s[c][e];
            ms += mes[c][e];
        }
        int p2 = r1;                                       // b2full = excl prefix of h2 + tot1
        for (int c = 0; c < NCHK; ++c) {
            ((int*)raw_base(out, c))[448 + e] = p2;
            p2 += h2s[c][e];
        }
        float term = (ms * (1.f / TOK)) * ((float)r1 * (1.f / TOK)) * (float)(NEXP * NEXP);
        term = wave_sum64(term);
        if (e == 0) out[0] = term * (1.f / NEXP);          // l_aux
    }
}

// ---- Phase 3: per-chunk ordered replay -> 16-B per-token records at the head of
//      each token-section output block (self-owned by phase 4's writer block).
__global__ __launch_bounds__(64) void tg_replay(float* __restrict__ out)
{
    const int e = threadIdx.x, c = blockIdx.x;
    float* raw = raw_base(out, c);
    const int   i12a = ((int*)raw)[e],  i12b = ((int*)raw)[64 + e];
    const float G1a = raw[128 + e], G1b = raw[192 + e];
    const float G2a = raw[256 + e], G2b = raw[320 + e];
    int cnt1 = ((int*)raw)[384 + e];
    int cnt2 = ((int*)raw)[448 + e];                       // already includes +tot1

    int   rA0 = 0, rA1 = 0, rB0 = 0, rB1 = 0;
    float rA2 = 0.f, rA3 = 0.f, rB2 = 0.f, rB3 = 0.f;

    for (int s = 0; s < CHK; ++s) {
        const int src = s & 63;
        const int   i12 = __shfl((s < 64) ? i12a : i12b, src);
        const float G1  = __shfl((s < 64) ? G1a  : G1b,  src);
        const float G2  = __shfl((s < 64) ? G2a  : G2b,  src);
        const int i1 = i12 & 255, i2 = (i12 >> 8) & 255;

        const int loc1 = __shfl(cnt1, i1);
        const int loc2 = __shfl(cnt2, i2);
        cnt1 += (e == i1);
        cnt2 += (e == i2);

        const bool k1 = loc1 < CAPC, k2 = loc2 < CAPC;
        const float ge1 = k1 ? G1 : 0.f, ge2 = k2 ? G2 : 0.f;
        const float dn  = fmaxf(ge1 + ge2, EPSF);          // post-drop renormalization
        const int rec0 = i1 | (i2 << 8) | (k1 ? (1 << 16) : 0) | (k2 ? (1 << 17) : 0);
        const int rec1 = (k1 ? loc1 : 0) | ((k2 ? loc2 : 0) << 16);
        const float w1 = ge1 / dn, w2 = ge2 / dn;

        if (src == e) {
            if (s < 64) { rA0 = rec0; rA1 = rec1; rA2 = w1; rA3 = w2; }
            else        { rB0 = rec0; rB1 = rec1; rB2 = w1; rB3 = w2; }
        }
    }

    const long long sA = (long long)c * CHK + e, sB = sA + 64;
    float* pA = out + 1 + sA * TBLK;       float* pB = out + 1 + sB * TBLK;
    float* qA = out + 1 + SEC + sA * TBLK; float* qB = out + 1 + SEC + sB * TBLK;
    ((int*)pA)[0] = rA0; ((int*)pA)[1] = rA1; pA[2] = rA2; pA[3] = rA3;
    ((int*)qA)[0] = rA0; ((int*)qA)[1] = rA1; qA[2] = rA2; qA[3] = rA3;
    ((int*)pB)[0] = rB0; ((int*)pB)[1] = rB1; pB[2] = rB2; pB[3] = rB3;
    ((int*)qB)[0] = rB0; ((int*)qB)[1] = rB1; qB[2] = rB2; qB[3] = rB3;
}

// ---- Phase 4: dense writer. One block per (token,section) 64KB block; every word
//      written exactly once (zero or fused nonzero). Fully coalesced dword streams.
__global__ __launch_bounds__(256) void tg_write(float* __restrict__ out)
{
    const int tid = threadIdx.x;
    const int b   = blockIdx.x;            // 0..16383
    const int sec = b >> 13;               // 0 = combine, 1 = dispatch
    const int s   = b & (TOK - 1);
    float* base = out + 1 + (long long)sec * SEC + (long long)s * TBLK;

    const int   rec0 = ((const int*)base)[0];
    const int   rec1 = ((const int*)base)[1];
    const float rw1  = base[2];
    const float rw2  = base[3];
    __syncthreads();                       // all reads done before words 0..3 get overwritten

    const int  i1 = rec0 & 255, i2 = (rec0 >> 8) & 255;
    const bool k1 = (rec0 >> 16) & 1, k2 = (rec0 >> 17) & 1;
    const int  pos1 = i1 * CAPC + (rec1 & 0xffff);
    const int  pos2 = i2 * CAPC + (rec1 >> 16);
    const float v1 = sec ? 1.f : rw1;
    const float v2 = sec ? 1.f : rw2;

    #pragma unroll
    for (int i = 0; i < 64; ++i) {
        const int idx = i * 256 + tid;
        float v = 0.f;
        if (k1 && idx == pos1) v = v1;
        if (k2 && idx == pos2) v = v2;
        base[idx] = v;
    }
}

extern "C" void kernel_launch(void* const* d_in, const int* in_sizes, int n_in,
                              void* d_out, int out_size, void* d_ws, size_t ws_size,
                              hipStream_t stream)
{
    (void)d_ws; (void)ws_size; (void)in_sizes; (void)n_in; (void)out_size;
    const float* logits = (const float*)d_in[0];
    const float* noise  = (const float*)d_in[1];
    float* out = (float*)d_out;

    tg_gate  <<<NCHK,      256, 0, stream>>>(logits, noise, out);
    tg_prefix<<<1,         256, 0, stream>>>(out);
    tg_replay<<<NCHK,       64, 0, stream>>>(out);
    tg_write <<<2 * NCHK * CHK, 256, 0, stream>>>(out);   // 16384 blocks
}

// Round 5
// 294.644 us; speedup vs baseline: 1.0480x; 1.0480x over previous
//
#include <hip/hip_runtime.h>

// Top2Gating, S=8192, E=64, capacity=256. Output f32 flat:
//   [ l_aux (1) | combine (S*E*CAP) | dispatch (S*E*CAP) ]  = 1 + 2*SEC words.
// Dense-writer design, 16B-aligned: output split into 16384 windows of 16384
// words at w*16384 (64KB-aligned). Window w = token-block w shifted by +1 word;
// local word 0 ("straddle") = previous block's last element (or l_aux for w=0).
// Replay writes straddle words as FINAL values + a 4-word record per window;
// writer streams aligned float4s, fusing zeros + <=2 nonzeros + straddle.
// The buffer's last word (index 2*SEC) is written by replay directly.

namespace {
constexpr int  TOK  = 8192;
constexpr int  NEXP = 64;
constexpr int  CAPC = 256;
constexpr int  CHK  = 128;
constexpr int  NCHK = TOK / CHK;                    // 64
constexpr long long TBLK = (long long)NEXP * CAPC;  // 16384 words per window
constexpr long long TERR = (long long)CHK * TBLK;   // words per chunk territory
constexpr long long SEC  = (long long)TOK * TBLK;   // words per dense section
constexpr float NEGMIN = -3.402823466e38f;          // finfo(f32).min
constexpr float EPSF   = 1.1920929e-7f;             // finfo(f32).eps
// chunk raw record @ words [1..576) of chunk head (unchanged from r4):
//   i12[128]@0 g1[128]@128 g2[128]@256 h1/b1[64]@384 h2/b2full[64]@448 me[64]@512
// per-window record (words w*16384 + 0..4):
//   [0] straddle FINAL value  [1] rec0 = i1|i2<<8|k1<<16|k2<<17
//   [2] rec1 = loc1|loc2<<16  [3] v1 (f32)  [4] v2 (f32)
}

__device__ __forceinline__ float wave_max64(float v) {
    for (int o = 32; o; o >>= 1) v = fmaxf(v, __shfl_xor(v, o));
    return v;
}
__device__ __forceinline__ float wave_sum64(float v) {
    for (int o = 32; o; o >>= 1) v += __shfl_xor(v, o);
    return v;
}
__device__ __forceinline__ float* raw_base(float* out, int c) { return out + 1 + (long long)c * TERR; }

// ---- Phase 1: per-row softmax + top1/top2 (first-max semantics), per-chunk hist/me.
__global__ __launch_bounds__(256) void tg_gate(const float* __restrict__ logits,
                                               const float* __restrict__ noise,
                                               float* __restrict__ out)
{
    __shared__ int   h1[NEXP], h2[NEXP];
    __shared__ float meSh[256];
    const int tid = threadIdx.x, lane = tid & 63, wv = tid >> 6;
    const int c = blockIdx.x;
    float* raw = raw_base(out, c);

    if (tid < NEXP) { h1[tid] = 0; h2[tid] = 0; }
    __syncthreads();

    float meAcc = 0.f;
    for (int i = 0; i < CHK / 4; ++i) {
        const int rloc = i * 4 + wv;
        const int row  = c * CHK + rloc;
        const float l = logits[row * NEXP + lane];
        const float n = noise [row * NEXP + lane];

        const float m    = wave_max64(l);
        const float ex   = __expf(l - m);
        const float sm   = wave_sum64(ex);
        const float gate = ex / sm;

        const unsigned long long b1 = __ballot(l == m);    // argmax(gates)==argmax(logits)
        const int   i1 = __ffsll(b1) - 1;                  // first max wins (jnp.argmax)
        const float G1 = __shfl(gate, i1);

        const float lw = (lane == i1) ? NEGMIN : (l + n);  // mask winner with finfo.min
        const float m2 = wave_max64(lw);
        const unsigned long long b2 = __ballot(lw == m2);
        const int   i2 = __ffsll(b2) - 1;
        const float G2 = __shfl(gate, i2);

        if (lane == 0) {
            ((int*)raw)[rloc] = i1 | (i2 << 8);
            raw[128 + rloc]   = G1;
            raw[256 + rloc]   = G2;
            atomicAdd(&h1[i1], 1);
            atomicAdd(&h2[i2], 1);
        }
        meAcc += gate;
    }

    meSh[tid] = meAcc;
    __syncthreads();
    if (tid < NEXP) {
        ((int*)raw)[384 + tid] = h1[tid];
        ((int*)raw)[448 + tid] = h2[tid];
        raw[512 + tid] = meSh[tid] + meSh[64 + tid] + meSh[128 + tid] + meSh[192 + tid];
    }
}

// ---- Phase 2: LDS-staged cross-chunk exclusive scan; bases written in place of
//      h1/h2; l_aux -> out[0].
__global__ __launch_bounds__(256) void tg_prefix(float* __restrict__ out)
{
    __shared__ int   h1s[NCHK][NEXP];
    __shared__ int   h2s[NCHK][NEXP];
    __shared__ float mes[NCHK][NEXP];
    const int tid = threadIdx.x;

    for (int n = tid; n < NCHK * 192; n += 256) {
        const int c = n / 192, w = n % 192;
        float* raw = raw_base(out, c);
        if      (w < 64)  h1s[c][w]       = ((int*)raw)[384 + w];
        else if (w < 128) h2s[c][w - 64]  = ((int*)raw)[384 + w];
        else              mes[c][w - 128] = raw[384 + w];
    }
    __syncthreads();

    if (tid < NEXP) {
        const int e = tid;
        int r1 = 0, r2 = 0;
        float ms = 0.f;
        for (int c = 0; c < NCHK; ++c) {                   // b1 = exclusive prefix of h1
            ((int*)raw_base(out, c))[384 + e] = r1;
            r1 += h1s[c][e];
            r2 += h2s[c][e];
            ms += mes[c][e];
        }
        int p2 = r1;                                       // b2full = excl prefix of h2 + tot1
        for (int c = 0; c < NCHK; ++c) {
            ((int*)raw_base(out, c))[448 + e] = p2;
            p2 += h2s[c][e];
        }
        float term = (ms * (1.f / TOK)) * ((float)r1 * (1.f / TOK)) * (float)(NEXP * NEXP);
        term = wave_sum64(term);
        if (e == 0) out[0] = term * (1.f / NEXP);          // l_aux
    }
}

__device__ __forceinline__ void emit_token(float* __restrict__ out, int s,
                                           int rec0, int rec1, float w1, float w2)
{
    const bool k1 = (rec0 >> 16) & 1, k2 = (rec0 >> 17) & 1;
    const int  i1 = rec0 & 255, i2 = (rec0 >> 8) & 255;
    const int  j1 = k1 ? (i1 * CAPC + (rec1 & 0xffff) + 1) : -1;  // window-local word
    const int  j2 = k2 ? (i2 * CAPC + (rec1 >> 16) + 1) : -1;

    // sec0 (combine): window s
    long long h = (long long)s * TBLK;
    ((int*)out)[h + 1] = rec0;
    ((int*)out)[h + 2] = rec1;
    out[h + 3] = w1;
    out[h + 4] = w2;
    out[h + TBLK] = (j1 == (int)TBLK) ? w1 : ((j2 == (int)TBLK) ? w2 : 0.f);

    // sec1 (dispatch): window TOK + s
    h = (long long)(TOK + s) * TBLK;
    ((int*)out)[h + 1] = rec0;
    ((int*)out)[h + 2] = rec1;
    out[h + 3] = 1.f;
    out[h + 4] = 1.f;
    out[h + TBLK] = (j1 == (int)TBLK || j2 == (int)TBLK) ? 1.f : 0.f;
}

// ---- Phase 3: per-chunk ordered replay -> per-window records + straddle words.
__global__ __launch_bounds__(64) void tg_replay(float* __restrict__ out)
{
    const int e = threadIdx.x, c = blockIdx.x;
    float* raw = raw_base(out, c);
    const int   i12a = ((int*)raw)[e],  i12b = ((int*)raw)[64 + e];
    const float G1a = raw[128 + e], G1b = raw[192 + e];
    const float G2a = raw[256 + e], G2b = raw[320 + e];
    int cnt1 = ((int*)raw)[384 + e];
    int cnt2 = ((int*)raw)[448 + e];                       // already includes +tot1

    int   rA0 = 0, rA1 = 0, rB0 = 0, rB1 = 0;
    float rA2 = 0.f, rA3 = 0.f, rB2 = 0.f, rB3 = 0.f;

    for (int s = 0; s < CHK; ++s) {
        const int src = s & 63;
        const int   i12 = __shfl((s < 64) ? i12a : i12b, src);
        const float G1  = __shfl((s < 64) ? G1a  : G1b,  src);
        const float G2  = __shfl((s < 64) ? G2a  : G2b,  src);
        const int i1 = i12 & 255, i2 = (i12 >> 8) & 255;

        const int loc1 = __shfl(cnt1, i1);
        const int loc2 = __shfl(cnt2, i2);
        cnt1 += (e == i1);
        cnt2 += (e == i2);

        const bool k1 = loc1 < CAPC, k2 = loc2 < CAPC;
        const float ge1 = k1 ? G1 : 0.f, ge2 = k2 ? G2 : 0.f;
        const float dn  = fmaxf(ge1 + ge2, EPSF);          // post-drop renormalization
        const int rec0 = i1 | (i2 << 8) | (k1 ? (1 << 16) : 0) | (k2 ? (1 << 17) : 0);
        const int rec1 = (k1 ? loc1 : 0) | ((k2 ? loc2 : 0) << 16);
        const float w1 = ge1 / dn, w2 = ge2 / dn;

        if (src == e) {
            if (s < 64) { rA0 = rec0; rA1 = rec1; rA2 = w1; rA3 = w2; }
            else        { rB0 = rec0; rB1 = rec1; rB2 = w1; rB3 = w2; }
        }
    }

    emit_token(out, c * CHK + e,      rA0, rA1, rA2, rA3);
    emit_token(out, c * CHK + 64 + e, rB0, rB1, rB2, rB3);
}

// ---- Phase 4: dense writer. One block per 64KB-aligned window; reads its 5-word
//      record, then streams 4096 aligned float4s (zeros + fused nonzeros + straddle).
__global__ __launch_bounds__(256) void tg_write(float* __restrict__ out)
{
    const int tid = threadIdx.x;
    const int w   = blockIdx.x;                            // 0..16383
    float* base = out + (long long)w * TBLK;               // 64KB-aligned

    const float4 A  = ((const float4*)base)[0];            // words 0..3
    const float  v2 = base[4];                             // word 4
    __syncthreads();                                       // reads drained before overwrite

    const float sv  = A.x;
    const int  rec0 = __float_as_int(A.y);
    const int  rec1 = __float_as_int(A.z);
    const float v1  = A.w;
    const bool k1 = (rec0 >> 16) & 1, k2 = (rec0 >> 17) & 1;
    const int  i1 = rec0 & 255, i2 = (rec0 >> 8) & 255;
    const int  j1 = k1 ? (i1 * CAPC + (rec1 & 0xffff) + 1) : -1;
    const int  j2 = k2 ? (i2 * CAPC + (rec1 >> 16) + 1) : -1;

    float4* b4 = (float4*)base;
    #pragma unroll
    for (int i = 0; i < 16; ++i) {
        const int q = i * 256 + tid;
        const int j = q * 4;
        float4 v;
        v.x = (j     == j1) ? v1 : ((j     == j2) ? v2 : 0.f);
        v.y = (j + 1 == j1) ? v1 : ((j + 1 == j2) ? v2 : 0.f);
        v.z = (j + 2 == j1) ? v1 : ((j + 2 == j2) ? v2 : 0.f);
        v.w = (j + 3 == j1) ? v1 : ((j + 3 == j2) ? v2 : 0.f);
        if (q == 0) v.x = sv;                              // preserve straddle/l_aux
        b4[q] = v;
    }
}

extern "C" void kernel_launch(void* const* d_in, const int* in_sizes, int n_in,
                              void* d_out, int out_size, void* d_ws, size_t ws_size,
                              hipStream_t stream)
{
    (void)d_ws; (void)ws_size; (void)in_sizes; (void)n_in; (void)out_size;
    const float* logits = (const float*)d_in[0];
    const float* noise  = (const float*)d_in[1];
    float* out = (float*)d_out;

    tg_gate  <<<NCHK, 256, 0, stream>>>(logits, noise, out);
    tg_prefix<<<1,    256, 0, stream>>>(out);
    tg_replay<<<NCHK,  64, 0, stream>>>(out);
    tg_write <<<2 * TOK, 256, 0, stream>>>(out);           // 16384 windows
}

// Round 7
// 260.397 us; speedup vs baseline: 1.1858x; 1.1315x over previous
//
#include <hip/hip_runtime.h>

// Top2Gating, S=8192, E=64, capacity=256. Output f32 flat:
//   [ l_aux (1) | combine (S*E*CAP) | dispatch (S*E*CAP) ] = 1 + 2*SEC words.
// Window design: output = 16384 windows of 16384 words at w*TBLK (64KB-aligned).
// Window w word 0 ("straddle") = previous token-block's last element (l_aux for w=0).
// All small kernels are fully parallel (ballot-match ranks, no serial replay).
// tg_write streams the whole buffer once with nontemporal float4 stores.

namespace {
constexpr int  TOK  = 8192;
constexpr int  NEXP = 64;
constexpr int  CAPC = 256;
constexpr int  CHK  = 128;
constexpr int  NCHK = TOK / CHK;                    // 64
constexpr long long TBLK = (long long)NEXP * CAPC;  // 16384 words per window
constexpr long long TERR = (long long)CHK * TBLK;   // words per chunk territory
constexpr long long SEC  = (long long)TOK * TBLK;   // words per dense section
constexpr float NEGMIN = -3.402823466e38f;          // finfo(f32).min
constexpr float EPSF   = 1.1920929e-7f;             // finfo(f32).eps
// chunk raw record @ words [1..576) of window c*CHK:
//   rec[128]@0 (i1|i2<<8|rank1<<16|rank2<<24)  g1[128]@128  g2[128]@256
//   h1[64]@384  h2[64]@448  me[64]@512
// bases table: 8192 ints at words [8, 8200) of window 16383
//   (only words 0..4 of any window are read by tg_write, so this is safe scratch)
constexpr long long BASES_OFF = 16383LL * 16384LL + 8;
// per-window record (words w*TBLK + 0..4):
//   [0] straddle FINAL value  [1] rec0=i1|i2<<8|k1<<16|k2<<17
//   [2] rec1=loc1|loc2<<16    [3] v1  [4] v2
}

typedef float f32x4 __attribute__((ext_vector_type(4)));  // clang vector: valid for nontemporal builtins

__device__ __forceinline__ float wave_max64(float v) {
    for (int o = 32; o; o >>= 1) v = fmaxf(v, __shfl_xor(v, o));
    return v;
}
__device__ __forceinline__ float wave_sum64(float v) {
    for (int o = 32; o; o >>= 1) v += __shfl_xor(v, o);
    return v;
}

// ---- Phase 1: gating + fully-parallel within-chunk ranks via ballot-match.
__global__ __launch_bounds__(256) void tg_gate(const float* __restrict__ logits,
                                               const float* __restrict__ noise,
                                               float* __restrict__ out)
{
    __shared__ int   i12s[CHK];
    __shared__ int   cntA[2][NEXP];    // first-half per-expert counts [choice][e]
    __shared__ int   cntB[2][NEXP];    // second-half
    __shared__ short r2s[CHK];
    __shared__ float meSh[256];
    const int tid = threadIdx.x, lane = tid & 63, wv = tid >> 6;
    const int c = blockIdx.x;
    float* raw = out + 1 + (long long)c * TERR;
    int*  rawi = (int*)raw;

    float meAcc = 0.f;
    for (int i = 0; i < CHK / 4; ++i) {
        const int rloc = i * 4 + wv;
        const int row  = c * CHK + rloc;
        const float l = logits[row * NEXP + lane];
        const float n = noise [row * NEXP + lane];

        const float m    = wave_max64(l);
        const float ex   = __expf(l - m);
        const float sm   = wave_sum64(ex);
        const float gate = ex / sm;

        const unsigned long long b1 = __ballot(l == m);     // argmax(gates)==argmax(logits)
        const int   i1 = __ffsll(b1) - 1;                   // first max wins
        const float G1 = __shfl(gate, i1);

        const float lw = (lane == i1) ? NEGMIN : (l + n);   // mask winner with finfo.min
        const float m2 = wave_max64(lw);
        const unsigned long long b2 = __ballot(lw == m2);
        const int   i2 = __ffsll(b2) - 1;
        const float G2 = __shfl(gate, i2);

        if (lane == 0) {
            i12s[rloc]        = i1 | (i2 << 8);
            raw[128 + rloc]   = G1;
            raw[256 + rloc]   = G2;
        }
        meAcc += gate;
    }
    meSh[tid] = meAcc;
    if (tid < 128) cntA[tid >> 6][tid & 63] = 0;
    else           cntB[(tid - 128) >> 6][tid & 63] = 0;
    __syncthreads();

    // match phase: wave {0,1}=first-choice halves {A,B}; {2,3}=second-choice {A,B}
    const int half = wv & 1;
    const int sel  = wv >> 1;                       // 0=first choice, 1=second
    const int t    = half * 64 + lane;              // token within chunk
    const int pk   = i12s[t];
    const int e    = sel ? ((pk >> 8) & 255) : (pk & 255);
    unsigned long long m = ~0ull;
    #pragma unroll
    for (int b = 0; b < 6; ++b) {
        const unsigned long long bb = __ballot((e >> b) & 1);
        m &= ((e >> b) & 1) ? bb : ~bb;             // lanes choosing same expert
    }
    const unsigned long long below = (1ull << lane) - 1;
    int lr = __popcll(m & below);                   // rank among earlier same-expert tokens
    if ((m & below) == 0) {                         // group leader records group size
        int (*cnt)[NEXP] = half ? cntB : cntA;
        cnt[sel][e] = __popcll(m);
    }
    __syncthreads();
    if (half) lr += cntA[sel][e];                   // second half: add first-half count
    if (sel)  r2s[t] = (short)lr;
    __syncthreads();
    if (!sel) rawi[t] = (pk & 0xffff) | (lr << 16) | (((int)r2s[t]) << 24);
    if (tid < NEXP) {
        rawi[384 + tid] = cntA[0][tid] + cntB[0][tid];          // h1
        rawi[448 + tid] = cntA[1][tid] + cntB[1][tid];          // h2
        raw [512 + tid] = meSh[tid] + meSh[64 + tid] + meSh[128 + tid] + meSh[192 + tid];
    }
}

// ---- Phase 2: tiny cross-chunk scan -> compact bases table + l_aux.
__global__ __launch_bounds__(256) void tg_scan(float* __restrict__ out)
{
    __shared__ int   h1s[NCHK][NEXP];
    __shared__ int   h2s[NCHK][NEXP];
    __shared__ float mes[NCHK][NEXP];
    const int tid = threadIdx.x;
    for (int n = tid; n < NCHK * 192; n += 256) {
        const int c = n / 192, w = n % 192;
        const float* raw = out + 1 + (long long)c * TERR;
        if      (w < 64)  h1s[c][w]       = ((const int*)raw)[384 + w];
        else if (w < 128) h2s[c][w - 64]  = ((const int*)raw)[384 + w];
        else              mes[c][w - 128] = raw[384 + w];
    }
    __syncthreads();
    if (tid < NEXP) {
        const int e = tid;
        int* WB = (int*)out + BASES_OFF;
        int r1 = 0, r2 = 0;
        float ms = 0.f;
        for (int c = 0; c < NCHK; ++c) {              // base1 = excl prefix of h1
            WB[c * 64 + e] = r1;
            r1 += h1s[c][e]; r2 += h2s[c][e]; ms += mes[c][e];
        }
        int p2 = r1;                                  // b2full = excl prefix of h2 + tot1
        for (int c = 0; c < NCHK; ++c) {
            WB[4096 + c * 64 + e] = p2;
            p2 += h2s[c][e];
        }
        float term = (ms * (1.f / TOK)) * ((float)r1 * (1.f / TOK)) * (float)(NEXP * NEXP);
        term = wave_sum64(term);
        if (e == 0) out[0] = term * (1.f / NEXP);     // l_aux (window 0 straddle)
    }
}

__device__ __forceinline__ void emit_token(float* __restrict__ out, int s,
                                           int rec0, int rec1, float w1, float w2)
{
    const bool k1 = (rec0 >> 16) & 1, k2 = (rec0 >> 17) & 1;
    const int  i1 = rec0 & 255, i2 = (rec0 >> 8) & 255;
    const int  j1 = k1 ? (i1 * CAPC + (rec1 & 0xffff) + 1) : -1;
    const int  j2 = k2 ? (i2 * CAPC + (rec1 >> 16) + 1) : -1;

    long long h = (long long)s * TBLK;                 // combine window
    ((int*)out)[h + 1] = rec0;
    ((int*)out)[h + 2] = rec1;
    out[h + 3] = w1;
    out[h + 4] = w2;
    out[h + TBLK] = (j1 == (int)TBLK) ? w1 : ((j2 == (int)TBLK) ? w2 : 0.f);

    h = (long long)(TOK + s) * TBLK;                   // dispatch window
    ((int*)out)[h + 1] = rec0;
    ((int*)out)[h + 2] = rec1;
    out[h + 3] = 1.f;
    out[h + 4] = 1.f;
    out[h + TBLK] = (j1 == (int)TBLK || j2 == (int)TBLK) ? 1.f : 0.f;
}

// ---- Phase 3: parallel per-token finalize -> window records + straddles.
__global__ __launch_bounds__(256) void tg_emit(float* __restrict__ out)
{
    const int s = blockIdx.x * 256 + threadIdx.x;      // one thread per token
    const int c = s >> 7, t = s & 127;
    const float* raw = out + 1 + (long long)c * TERR;
    const int   pk = ((const int*)raw)[t];
    const float G1 = raw[128 + t];
    const float G2 = raw[256 + t];
    const int* WB = (const int*)out + BASES_OFF;
    const int i1 = pk & 255, i2 = (pk >> 8) & 255;
    const int loc1 = WB[c * 64 + i1]        + ((pk >> 16) & 255);
    const int loc2 = WB[4096 + c * 64 + i2] + ((pk >> 24) & 255);
    __syncthreads();   // this block's raw reads done before records overwrite raw homes

    const bool k1 = loc1 < CAPC, k2 = loc2 < CAPC;
    const float ge1 = k1 ? G1 : 0.f, ge2 = k2 ? G2 : 0.f;
    const float dn  = fmaxf(ge1 + ge2, EPSF);          // post-drop renormalization
    const int rec0 = i1 | (i2 << 8) | (k1 ? 1 << 16 : 0) | (k2 ? 1 << 17 : 0);
    const int rec1 = (k1 ? loc1 : 0) | ((k2 ? loc2 : 0) << 16);
    emit_token(out, s, rec0, rec1, ge1 / dn, ge2 / dn);
}

// ---- Phase 4: dense writer, nontemporal float4 stream (zeros + fused nonzeros).
__global__ __launch_bounds__(256) void tg_write(float* __restrict__ out)
{
    const int tid = threadIdx.x;
    const int w   = blockIdx.x;                        // 0..16383
    float* base = out + (long long)w * TBLK;           // 64KB-aligned

    const f32x4 A = __builtin_nontemporal_load((const f32x4*)base);
    const float v2 = base[4];
    __syncthreads();

    const float sv  = A.x;
    const int  rec0 = __float_as_int(A.y);
    const int  rec1 = __float_as_int(A.z);
    const float v1  = A.w;
    const bool k1 = (rec0 >> 16) & 1, k2 = (rec0 >> 17) & 1;
    const int  i1 = rec0 & 255, i2 = (rec0 >> 8) & 255;
    const int  j1 = k1 ? (i1 * CAPC + (rec1 & 0xffff) + 1) : -1;
    const int  j2 = k2 ? (i2 * CAPC + (rec1 >> 16) + 1) : -1;

    f32x4* b4 = (f32x4*)base;
    #pragma unroll
    for (int i = 0; i < 16; ++i) {
        const int q = i * 256 + tid;
        const int j = q * 4;
        f32x4 v;
        v.x = (j     == j1) ? v1 : ((j     == j2) ? v2 : 0.f);
        v.y = (j + 1 == j1) ? v1 : ((j + 1 == j2) ? v2 : 0.f);
        v.z = (j + 2 == j1) ? v1 : ((j + 2 == j2) ? v2 : 0.f);
        v.w = (j + 3 == j1) ? v1 : ((j + 3 == j2) ? v2 : 0.f);
        if (q == 0) v.x = sv;                          // preserve straddle / l_aux
        __builtin_nontemporal_store(v, &b4[q]);
    }
}

extern "C" void kernel_launch(void* const* d_in, const int* in_sizes, int n_in,
                              void* d_out, int out_size, void* d_ws, size_t ws_size,
                              hipStream_t stream)
{
    (void)d_ws; (void)ws_size; (void)in_sizes; (void)n_in; (void)out_size;
    const float* logits = (const float*)d_in[0];
    const float* noise  = (const float*)d_in[1];
    float* out = (float*)d_out;

    tg_gate <<<NCHK,      256, 0, stream>>>(logits, noise, out);
    tg_scan <<<1,         256, 0, stream>>>(out);
    tg_emit <<<TOK / 256, 256, 0, stream>>>(out);
    tg_write<<<2 * TOK,   256, 0, stream>>>(out);
}

// Round 8
// 246.312 us; speedup vs baseline: 1.2536x; 1.0572x over previous
//
#include <hip/hip_runtime.h>

// Top2Gating, S=8192, E=64, capacity=256. Output f32 flat:
//   [ l_aux (1) | combine (S*E*CAP) | dispatch (S*E*CAP) ] = 1 + 2*SEC words.
// Window design: output = 16384 windows of 16384 words at w*TBLK (64KB-aligned).
// Window w word 0 ("straddle") = previous token-block's last element (l_aux for w=0).
// tg_gate: 1024 thr/block for latency hiding; ballot-match ranks (no serial replay).
// tg_write streams the whole buffer once with nontemporal float4 stores.

namespace {
constexpr int  TOK  = 8192;
constexpr int  NEXP = 64;
constexpr int  CAPC = 256;
constexpr int  CHK  = 128;
constexpr int  NCHK = TOK / CHK;                    // 64
constexpr long long TBLK = (long long)NEXP * CAPC;  // 16384 words per window
constexpr long long TERR = (long long)CHK * TBLK;   // words per chunk territory
constexpr long long SEC  = (long long)TOK * TBLK;   // words per dense section
constexpr float NEGMIN = -3.402823466e38f;          // finfo(f32).min
constexpr float EPSF   = 1.1920929e-7f;             // finfo(f32).eps
// chunk raw record @ words [1..576) of window c*CHK:
//   rec[128]@0 (i1|i2<<8|rank1<<16|rank2<<24)  g1[128]@128  g2[128]@256
//   h1[64]@384  h2[64]@448  me[64]@512
// bases table: 8192 ints at words [8, 8200) of window 16383
//   (only words 0..4 of any window are read by tg_write, so this is safe scratch)
constexpr long long BASES_OFF = 16383LL * 16384LL + 8;
// per-window record (words w*TBLK + 0..4):
//   [0] straddle FINAL value  [1] rec0=i1|i2<<8|k1<<16|k2<<17
//   [2] rec1=loc1|loc2<<16    [3] v1  [4] v2
}

typedef float f32x4 __attribute__((ext_vector_type(4)));

__device__ __forceinline__ float wave_max64(float v) {
    for (int o = 32; o; o >>= 1) v = fmaxf(v, __shfl_xor(v, o));
    return v;
}
__device__ __forceinline__ float wave_sum64(float v) {
    for (int o = 32; o; o >>= 1) v += __shfl_xor(v, o);
    return v;
}

// ---- Phase 1: gating + parallel within-chunk ranks. 1024 threads (16 waves):
//      8 row-iterations per wave -> 4 waves/SIMD-group occupancy for latency hiding.
__global__ __launch_bounds__(1024) void tg_gate(const float* __restrict__ logits,
                                                const float* __restrict__ noise,
                                                float* __restrict__ out)
{
    __shared__ int   i12s[CHK];
    __shared__ int   cntA[2][NEXP];    // first-half per-expert counts [choice][e]
    __shared__ int   cntB[2][NEXP];    // second-half
    __shared__ int   lrS[2][2][64];    // local rank [sel][half][lane]
    __shared__ float meSh[1024];
    const int tid = threadIdx.x, lane = tid & 63, wv = tid >> 6;   // 16 waves
    const int c = blockIdx.x;
    float* raw = out + 1 + (long long)c * TERR;
    int*  rawi = (int*)raw;

    float meAcc = 0.f;
    #pragma unroll
    for (int i = 0; i < CHK / 16; ++i) {            // 8 iterations
        const int rloc = i * 16 + wv;
        const int row  = c * CHK + rloc;
        const float l = logits[row * NEXP + lane];
        const float n = noise [row * NEXP + lane];

        const float m    = wave_max64(l);
        const float ex   = __expf(l - m);
        const float sm   = wave_sum64(ex);
        const float gate = ex / sm;

        const unsigned long long b1 = __ballot(l == m);     // argmax(gates)==argmax(logits)
        const int   i1 = __ffsll(b1) - 1;                   // first max wins
        const float G1 = __shfl(gate, i1);

        const float lw = (lane == i1) ? NEGMIN : (l + n);   // mask winner with finfo.min
        const float m2 = wave_max64(lw);
        const unsigned long long b2 = __ballot(lw == m2);
        const int   i2 = __ffsll(b2) - 1;
        const float G2 = __shfl(gate, i2);

        if (lane == 0) {
            i12s[rloc]      = i1 | (i2 << 8);
            raw[128 + rloc] = G1;
            raw[256 + rloc] = G2;
        }
        meAcc += gate;
    }
    meSh[tid] = meAcc;
    if      (tid < 128) cntA[tid >> 6][tid & 63] = 0;
    else if (tid < 256) cntB[(tid - 128) >> 6][tid & 63] = 0;
    __syncthreads();

    // match phase (waves 0..3): wave = {sel,half}; per-wave ballot-match ranks.
    if (wv < 4) {
        const int half = wv & 1;
        const int sel  = wv >> 1;                   // 0=first choice, 1=second
        const int t    = half * 64 + lane;
        const int pk   = i12s[t];
        const int e    = sel ? ((pk >> 8) & 255) : (pk & 255);
        unsigned long long m = ~0ull;
        #pragma unroll
        for (int b = 0; b < 6; ++b) {
            const unsigned long long bb = __ballot((e >> b) & 1);
            m &= ((e >> b) & 1) ? bb : ~bb;         // lanes choosing same expert
        }
        const unsigned long long below = (1ull << lane) - 1;
        lrS[sel][half][lane] = __popcll(m & below); // rank among earlier same-expert
        if ((m & below) == 0) {                     // group leader records group size
            (half ? cntB : cntA)[sel][e] = __popcll(m);
        }
    }
    __syncthreads();

    if (tid < 128) {                                // pack rec with global-in-chunk ranks
        const int t = tid, pk = i12s[t];
        const int h = t >> 6, ln = t & 63;
        const int e1 = pk & 255, e2 = (pk >> 8) & 255;
        const int r1 = lrS[0][h][ln] + (h ? cntA[0][e1] : 0);
        const int r2 = lrS[1][h][ln] + (h ? cntA[1][e2] : 0);
        rawi[t] = (pk & 0xffff) | (r1 << 16) | (r2 << 24);
    }
    if (tid < NEXP) {
        rawi[384 + tid] = cntA[0][tid] + cntB[0][tid];          // h1
        rawi[448 + tid] = cntA[1][tid] + cntB[1][tid];          // h2
        float s = 0.f;
        #pragma unroll
        for (int w = 0; w < 16; ++w) s += meSh[w * 64 + tid];
        raw[512 + tid] = s;
    }
}

// ---- Phase 2: tiny cross-chunk scan -> compact bases table + l_aux.
__global__ __launch_bounds__(256) void tg_scan(float* __restrict__ out)
{
    __shared__ int   h1s[NCHK][NEXP];
    __shared__ int   h2s[NCHK][NEXP];
    __shared__ float mes[NCHK][NEXP];
    const int tid = threadIdx.x;
    for (int n = tid; n < NCHK * 192; n += 256) {
        const int c = n / 192, w = n % 192;
        const float* raw = out + 1 + (long long)c * TERR;
        if      (w < 64)  h1s[c][w]       = ((const int*)raw)[384 + w];
        else if (w < 128) h2s[c][w - 64]  = ((const int*)raw)[384 + w];
        else              mes[c][w - 128] = raw[384 + w];
    }
    __syncthreads();
    if (tid < NEXP) {
        const int e = tid;
        int* WB = (int*)out + BASES_OFF;
        int r1 = 0, r2 = 0;
        float ms = 0.f;
        for (int c = 0; c < NCHK; ++c) {              // base1 = excl prefix of h1
            WB[c * 64 + e] = r1;
            r1 += h1s[c][e]; r2 += h2s[c][e]; ms += mes[c][e];
        }
        int p2 = r1;                                  // b2full = excl prefix of h2 + tot1
        for (int c = 0; c < NCHK; ++c) {
            WB[4096 + c * 64 + e] = p2;
            p2 += h2s[c][e];
        }
        float term = (ms * (1.f / TOK)) * ((float)r1 * (1.f / TOK)) * (float)(NEXP * NEXP);
        term = wave_sum64(term);
        if (e == 0) out[0] = term * (1.f / NEXP);     // l_aux (window 0 straddle)
    }
}

__device__ __forceinline__ void emit_token(float* __restrict__ out, int s,
                                           int rec0, int rec1, float w1, float w2)
{
    const bool k1 = (rec0 >> 16) & 1, k2 = (rec0 >> 17) & 1;
    const int  i1 = rec0 & 255, i2 = (rec0 >> 8) & 255;
    const int  j1 = k1 ? (i1 * CAPC + (rec1 & 0xffff) + 1) : -1;
    const int  j2 = k2 ? (i2 * CAPC + (rec1 >> 16) + 1) : -1;

    long long h = (long long)s * TBLK;                 // combine window
    ((int*)out)[h + 1] = rec0;
    ((int*)out)[h + 2] = rec1;
    out[h + 3] = w1;
    out[h + 4] = w2;
    out[h + TBLK] = (j1 == (int)TBLK) ? w1 : ((j2 == (int)TBLK) ? w2 : 0.f);

    h = (long long)(TOK + s) * TBLK;                   // dispatch window
    ((int*)out)[h + 1] = rec0;
    ((int*)out)[h + 2] = rec1;
    out[h + 3] = 1.f;
    out[h + 4] = 1.f;
    out[h + TBLK] = (j1 == (int)TBLK || j2 == (int)TBLK) ? 1.f : 0.f;
}

// ---- Phase 3: parallel per-token finalize -> window records + straddles.
__global__ __launch_bounds__(256) void tg_emit(float* __restrict__ out)
{
    const int s = blockIdx.x * 256 + threadIdx.x;      // one thread per token
    const int c = s >> 7, t = s & 127;
    const float* raw = out + 1 + (long long)c * TERR;
    const int   pk = ((const int*)raw)[t];
    const float G1 = raw[128 + t];
    const float G2 = raw[256 + t];
    const int* WB = (const int*)out + BASES_OFF;
    const int i1 = pk & 255, i2 = (pk >> 8) & 255;
    const int loc1 = WB[c * 64 + i1]        + ((pk >> 16) & 255);
    const int loc2 = WB[4096 + c * 64 + i2] + ((pk >> 24) & 255);
    __syncthreads();   // this block's raw reads done before records overwrite raw homes

    const bool k1 = loc1 < CAPC, k2 = loc2 < CAPC;
    const float ge1 = k1 ? G1 : 0.f, ge2 = k2 ? G2 : 0.f;
    const float dn  = fmaxf(ge1 + ge2, EPSF);          // post-drop renormalization
    const int rec0 = i1 | (i2 << 8) | (k1 ? 1 << 16 : 0) | (k2 ? 1 << 17 : 0);
    const int rec1 = (k1 ? loc1 : 0) | ((k2 ? loc2 : 0) << 16);
    emit_token(out, s, rec0, rec1, ge1 / dn, ge2 / dn);
}

// ---- Phase 4: dense writer, nontemporal float4 stream (zeros + fused nonzeros).
__global__ __launch_bounds__(256) void tg_write(float* __restrict__ out)
{
    const int tid = threadIdx.x;
    const int w   = blockIdx.x;                        // 0..16383
    float* base = out + (long long)w * TBLK;           // 64KB-aligned

    const f32x4 A = __builtin_nontemporal_load((const f32x4*)base);
    const float v2 = base[4];
    __syncthreads();

    const float sv  = A.x;
    const int  rec0 = __float_as_int(A.y);
    const int  rec1 = __float_as_int(A.z);
    const float v1  = A.w;
    const bool k1 = (rec0 >> 16) & 1, k2 = (rec0 >> 17) & 1;
    const int  i1 = rec0 & 255, i2 = (rec0 >> 8) & 255;
    const int  j1 = k1 ? (i1 * CAPC + (rec1 & 0xffff) + 1) : -1;
    const int  j2 = k2 ? (i2 * CAPC + (rec1 >> 16) + 1) : -1;

    f32x4* b4 = (f32x4*)base;
    #pragma unroll
    for (int i = 0; i < 16; ++i) {
        const int q = i * 256 + tid;
        const int j = q * 4;
        f32x4 v;
        v.x = (j     == j1) ? v1 : ((j     == j2) ? v2 : 0.f);
        v.y = (j + 1 == j1) ? v1 : ((j + 1 == j2) ? v2 : 0.f);
        v.z = (j + 2 == j1) ? v1 : ((j + 2 == j2) ? v2 : 0.f);
        v.w = (j + 3 == j1) ? v1 : ((j + 3 == j2) ? v2 : 0.f);
        if (q == 0) v.x = sv;                          // preserve straddle / l_aux
        __builtin_nontemporal_store(v, &b4[q]);
    }
}

extern "C" void kernel_launch(void* const* d_in, const int* in_sizes, int n_in,
                              void* d_out, int out_size, void* d_ws, size_t ws_size,
                              hipStream_t stream)
{
    (void)d_ws; (void)ws_size; (void)in_sizes; (void)n_in; (void)out_size;
    const float* logits = (const float*)d_in[0];
    const float* noise  = (const float*)d_in[1];
    float* out = (float*)d_out;

    tg_gate <<<NCHK,      1024, 0, stream>>>(logits, noise, out);
    tg_scan <<<1,          256, 0, stream>>>(out);
    tg_emit <<<TOK / 256,  256, 0, stream>>>(out);
    tg_write<<<2 * TOK,    256, 0, stream>>>(out);
}

// Round 9
// 213.202 us; speedup vs baseline: 1.4483x; 1.1553x over previous
//
#include <hip/hip_runtime.h>

// Top2Gating, S=8192, E=64, capacity=256. Output f32 flat:
//   [ l_aux (1) | combine (S*E*CAP) | dispatch (S*E*CAP) ] = 1 + 2*SEC words.
// Window design: output = 16384 windows of 16384 words at w*TBLK (64KB-aligned).
// Window w word 0 ("straddle") = previous token-block's last element (l_aux for w=0).
// Compact scratch lives in words [8..) of windows 16380..16382 (dispatch tail):
// written by gate/scan, read by scan/emit, overwritten last by tg_write.
// tg_write: one WAVE per window -> no barriers; nontemporal float4 stream.

namespace {
constexpr int  TOK  = 8192;
constexpr int  NEXP = 64;
constexpr int  CAPC = 256;
constexpr int  CHK  = 128;
constexpr int  NCHK = TOK / CHK;                    // 64
constexpr long long TBLK = (long long)NEXP * CAPC;  // 16384 words per window
constexpr long long SEC  = (long long)TOK * TBLK;   // words per dense section
constexpr float NEGMIN = -3.402823466e38f;          // finfo(f32).min
constexpr float EPSF   = 1.1920929e-7f;             // finfo(f32).eps
// scratch (word offsets into out):
//   winA=16380: pk[8192]@+8   h12[4096]@+8200   (pk = i1|i2<<8|r1<<16|r2<<24)
//   winB=16381: G1[8192]@+8   me[4096]@+8200
//   winC=16382: G2[8192]@+8   b12[4096]@+8200   (b12 = b1 | b2full<<16)
constexpr long long PK_OFF  = 16380LL * 16384 + 8;
constexpr long long H12_OFF = 16380LL * 16384 + 8200;
constexpr long long G1_OFF  = 16381LL * 16384 + 8;
constexpr long long ME_OFF  = 16381LL * 16384 + 8200;
constexpr long long G2_OFF  = 16382LL * 16384 + 8;
constexpr long long B12_OFF = 16382LL * 16384 + 8200;
// per-window record (words w*TBLK + 0..4):
//   [0] straddle FINAL value  [1] rec0=i1|i2<<8|k1<<16|k2<<17
//   [2] rec1=loc1|loc2<<16    [3] v1  [4] v2
}

typedef float f32x4 __attribute__((ext_vector_type(4)));

__device__ __forceinline__ float wave_max64(float v) {
    for (int o = 32; o; o >>= 1) v = fmaxf(v, __shfl_xor(v, o));
    return v;
}
__device__ __forceinline__ float wave_sum64(float v) {
    for (int o = 32; o; o >>= 1) v += __shfl_xor(v, o);
    return v;
}

// ---- Phase 1: gating + parallel within-chunk ranks; compact coalesced outputs.
__global__ __launch_bounds__(1024) void tg_gate(const float* __restrict__ logits,
                                                const float* __restrict__ noise,
                                                float* __restrict__ out)
{
    __shared__ int   i12s[CHK];
    __shared__ float g1s[CHK], g2s[CHK];
    __shared__ int   cntA[2][NEXP];    // first-half per-expert counts [choice][e]
    __shared__ int   cntB[2][NEXP];    // second-half
    __shared__ int   lrS[2][2][64];    // local rank [sel][half][lane]
    __shared__ float meSh[1024];
    const int tid = threadIdx.x, lane = tid & 63, wv = tid >> 6;   // 16 waves
    const int c = blockIdx.x;

    float meAcc = 0.f;
    #pragma unroll
    for (int i = 0; i < CHK / 16; ++i) {            // 8 iterations
        const int rloc = i * 16 + wv;
        const int row  = c * CHK + rloc;
        const float l = logits[row * NEXP + lane];
        const float n = noise [row * NEXP + lane];

        const float m    = wave_max64(l);
        const float ex   = __expf(l - m);
        const float sm   = wave_sum64(ex);
        const float gate = ex / sm;

        const unsigned long long b1 = __ballot(l == m);     // argmax(gates)==argmax(logits)
        const int   i1 = __ffsll(b1) - 1;                   // first max wins
        const float G1 = __shfl(gate, i1);

        const float lw = (lane == i1) ? NEGMIN : (l + n);   // mask winner with finfo.min
        const float m2 = wave_max64(lw);
        const unsigned long long b2 = __ballot(lw == m2);
        const int   i2 = __ffsll(b2) - 1;
        const float G2 = __shfl(gate, i2);

        if (lane == 0) {
            i12s[rloc] = i1 | (i2 << 8);
            g1s[rloc]  = G1;
            g2s[rloc]  = G2;
        }
        meAcc += gate;
    }
    meSh[tid] = meAcc;
    if      (tid < 128) cntA[tid >> 6][tid & 63] = 0;
    else if (tid < 256) cntB[(tid - 128) >> 6][tid & 63] = 0;
    __syncthreads();

    // match phase (waves 0..3): wave = {sel,half}; per-wave ballot-match ranks.
    if (wv < 4) {
        const int half = wv & 1;
        const int sel  = wv >> 1;                   // 0=first choice, 1=second
        const int t    = half * 64 + lane;
        const int pk   = i12s[t];
        const int e    = sel ? ((pk >> 8) & 255) : (pk & 255);
        unsigned long long m = ~0ull;
        #pragma unroll
        for (int b = 0; b < 6; ++b) {
            const unsigned long long bb = __ballot((e >> b) & 1);
            m &= ((e >> b) & 1) ? bb : ~bb;         // lanes choosing same expert
        }
        const unsigned long long below = (1ull << lane) - 1;
        lrS[sel][half][lane] = __popcll(m & below); // rank among earlier same-expert
        if ((m & below) == 0) {                     // group leader records group size
            (half ? cntB : cntA)[sel][e] = __popcll(m);
        }
    }
    __syncthreads();

    int* outi = (int*)out;
    if (tid < 128) {                                // pack rec with global-in-chunk ranks
        const int t = tid, pk = i12s[t];
        const int h = t >> 6, ln = t & 63;
        const int e1 = pk & 255, e2 = (pk >> 8) & 255;
        const int r1 = lrS[0][h][ln] + (h ? cntA[0][e1] : 0);
        const int r2 = lrS[1][h][ln] + (h ? cntA[1][e2] : 0);
        outi[PK_OFF + c * CHK + t] = (pk & 0xffff) | (r1 << 16) | (r2 << 24);
        out [G1_OFF + c * CHK + t] = g1s[t];
        out [G2_OFF + c * CHK + t] = g2s[t];
    }
    if (tid < NEXP) {
        const int h1 = cntA[0][tid] + cntB[0][tid];
        const int h2 = cntA[1][tid] + cntB[1][tid];
        outi[H12_OFF + c * NEXP + tid] = h1 | (h2 << 16);
        float s = 0.f;
        #pragma unroll
        for (int w = 0; w < 16; ++w) s += meSh[w * 64 + tid];
        out[ME_OFF + c * NEXP + tid] = s;
    }
}

// ---- Phase 2: cross-chunk scan over compact tables -> b12 + l_aux. Coalesced.
__global__ __launch_bounds__(256) void tg_scan(float* __restrict__ out)
{
    __shared__ int   h1s[NCHK][NEXP];
    __shared__ int   h2s[NCHK][NEXP];
    __shared__ float mes[NCHK][NEXP];
    const int tid = threadIdx.x;
    const int* outi = (const int*)out;
    for (int n = tid; n < NCHK * NEXP; n += 256) {
        const int v = outi[H12_OFF + n];
        h1s[n >> 6][n & 63] = v & 0xffff;
        h2s[n >> 6][n & 63] = v >> 16;
        mes[n >> 6][n & 63] = out[ME_OFF + n];
    }
    __syncthreads();
    if (tid < NEXP) {
        const int e = tid;
        int r1 = 0, r2 = 0;
        float ms = 0.f;
        for (int c = 0; c < NCHK; ++c) {              // b1 = excl prefix of h1 (in place)
            const int h = h1s[c][e];
            h1s[c][e] = r1;
            r1 += h; r2 += h2s[c][e]; ms += mes[c][e];
        }
        int p2 = r1;                                  // b2full = excl prefix of h2 + tot1
        int* wbi = (int*)out;
        for (int c = 0; c < NCHK; ++c) {
            wbi[B12_OFF + c * NEXP + e] = h1s[c][e] | (p2 << 16);
            p2 += h2s[c][e];
        }
        float term = (ms * (1.f / TOK)) * ((float)r1 * (1.f / TOK)) * (float)(NEXP * NEXP);
        term = wave_sum64(term);
        if (e == 0) out[0] = term * (1.f / NEXP);     // l_aux (window 0 straddle)
    }
}

// ---- Phase 3: parallel per-token finalize -> window records + straddles.
__global__ __launch_bounds__(256) void tg_emit(float* __restrict__ out)
{
    const int s = blockIdx.x * 256 + threadIdx.x;      // one thread per token
    const int c = s >> 7;
    const int* outi = (const int*)out;
    const int   pk = outi[PK_OFF + s];
    const float G1 = out[G1_OFF + s];
    const float G2 = out[G2_OFF + s];
    const int i1 = pk & 255, i2 = (pk >> 8) & 255;
    const unsigned b1w = (unsigned)outi[B12_OFF + c * NEXP + i1];
    const unsigned b2w = (unsigned)outi[B12_OFF + c * NEXP + i2];
    const int loc1 = (int)(b1w & 0xffffu) + ((pk >> 16) & 255);
    const int loc2 = (int)(b2w >> 16)     + ((pk >> 24) & 255);

    const bool k1 = loc1 < CAPC, k2 = loc2 < CAPC;
    const float ge1 = k1 ? G1 : 0.f, ge2 = k2 ? G2 : 0.f;
    const float dn  = fmaxf(ge1 + ge2, EPSF);          // post-drop renormalization
    const float w1 = ge1 / dn, w2 = ge2 / dn;
    const int rec0 = i1 | (i2 << 8) | (k1 ? 1 << 16 : 0) | (k2 ? 1 << 17 : 0);
    const int rec1 = (k1 ? loc1 : 0) | ((k2 ? loc2 : 0) << 16);
    const int j1 = k1 ? (i1 * CAPC + (rec1 & 0xffff) + 1) : -1;  // window-local word
    const int j2 = k2 ? (i2 * CAPC + (rec1 >> 16) + 1) : -1;

    long long h = (long long)s * TBLK;                 // combine window
    ((int*)out)[h + 1] = rec0;
    ((int*)out)[h + 2] = rec1;
    out[h + 3] = w1;
    out[h + 4] = w2;
    out[h + TBLK] = (j1 == (int)TBLK) ? w1 : ((j2 == (int)TBLK) ? w2 : 0.f);

    h = (long long)(TOK + s) * TBLK;                   // dispatch window
    ((int*)out)[h + 1] = rec0;
    ((int*)out)[h + 2] = rec1;
    out[h + 3] = 1.f;
    out[h + 4] = 1.f;
    out[h + TBLK] = (j1 == (int)TBLK || j2 == (int)TBLK) ? 1.f : 0.f;
}

// ---- Phase 4: dense writer, one WAVE per window (no barriers). Each store
//      instruction: 64 lanes x 16B contiguous = 1KB. Nontemporal stream.
__global__ __launch_bounds__(256) void tg_write(float* __restrict__ out)
{
    const int lane = threadIdx.x & 63, wv = threadIdx.x >> 6;
    const int w = blockIdx.x * 4 + wv;                 // 0..16383
    float* base = out + (long long)w * TBLK;           // 64KB-aligned

    // wave-lockstep: these loads complete (waitcnt on use) before any store issues
    const f32x4 A  = *(const f32x4*)base;
    const float v2 = base[4];

    const float sv  = A.x;
    const int  rec0 = __float_as_int(A.y);
    const int  rec1 = __float_as_int(A.z);
    const float v1  = A.w;
    const bool k1 = (rec0 >> 16) & 1, k2 = (rec0 >> 17) & 1;
    const int  i1 = rec0 & 255, i2 = (rec0 >> 8) & 255;
    const int  j1 = k1 ? (i1 * CAPC + (rec1 & 0xffff) + 1) : -1;
    const int  j2 = k2 ? (i2 * CAPC + (rec1 >> 16) + 1) : -1;

    f32x4* b4 = (f32x4*)base;
    #pragma unroll
    for (int i = 0; i < 64; ++i) {
        const int q = i * 64 + lane;
        const int j = q * 4;
        f32x4 v;
        v.x = (j     == j1) ? v1 : ((j     == j2) ? v2 : 0.f);
        v.y = (j + 1 == j1) ? v1 : ((j + 1 == j2) ? v2 : 0.f);
        v.z = (j + 2 == j1) ? v1 : ((j + 2 == j2) ? v2 : 0.f);
        v.w = (j + 3 == j1) ? v1 : ((j + 3 == j2) ? v2 : 0.f);
        if (q == 0) v.x = sv;                          // preserve straddle / l_aux
        __builtin_nontemporal_store(v, &b4[q]);
    }
}

extern "C" void kernel_launch(void* const* d_in, const int* in_sizes, int n_in,
                              void* d_out, int out_size, void* d_ws, size_t ws_size,
                              hipStream_t stream)
{
    (void)d_ws; (void)ws_size; (void)in_sizes; (void)n_in; (void)out_size;
    const float* logits = (const float*)d_in[0];
    const float* noise  = (const float*)d_in[1];
    float* out = (float*)d_out;

    tg_gate <<<NCHK,      1024, 0, stream>>>(logits, noise, out);
    tg_scan <<<1,          256, 0, stream>>>(out);
    tg_emit <<<TOK / 256,  256, 0, stream>>>(out);
    tg_write<<<TOK / 2,    256, 0, stream>>>(out);     // 4096 blocks, 4 windows each
}